// Round 2
// baseline (487.113 us; speedup 1.0000x reference)
//
#include <hip/hip_runtime.h>
#include <math.h>

#define B_    8
#define C_H_  128
#define C_L_  256
#define K_    64
#define NPIX_L 16384          // 128*128
#define EPS_  1e-5f

// ws layout (float offsets)
#define P_OFF   0
#define P_SZ    (B_*K_*C_H_)      // 65536
#define CK_OFF  (P_OFF + P_SZ)
#define CK_SZ   (B_*K_*C_L_)      // 131072
#define CV_OFF  (CK_OFF + CK_SZ)
#define CV_SZ   (B_*C_L_*K_)      // 131072
#define SCL_OFF (CV_OFF + CV_SZ)
#define SHF_OFF (SCL_OFF + C_L_)

// ---------------- Kernel 1: BN + 8x8 max-pool of x_h -> p[b][k][c] ----------------
// BN is monotone: max(BN(x)) = BN(max x) if scale>=0 else BN(min x).
__global__ __launch_bounds__(256) void pool_bn_kernel(
    const float* __restrict__ x_h,
    const float* __restrict__ g, const float* __restrict__ be,
    const float* __restrict__ mn, const float* __restrict__ vr,
    float* __restrict__ ws)
{
    const int t   = threadIdx.x;
    const int k   = t & 63;        // pooled position
    const int cl  = t >> 6;        // 0..3
    const int bid = blockIdx.x;    // 256 blocks = 8 b * 32 cgroups
    const int b   = bid >> 5;
    const int c   = ((bid & 31) << 2) + cl;

    const float* plane = x_h + ((size_t)(b * C_H_ + c) << 12);   // *4096
    const int ph = k >> 3, pw = k & 7;
    const float* p0 = plane + (ph * 8) * 64 + pw * 8;

    float mx = -INFINITY, mnv = INFINITY;
#pragma unroll
    for (int i = 0; i < 8; i++) {
        const float4 a  = *reinterpret_cast<const float4*>(p0 + i * 64);
        const float4 bq = *reinterpret_cast<const float4*>(p0 + i * 64 + 4);
        mx  = fmaxf(mx,  fmaxf(fmaxf(a.x, a.y),  fmaxf(a.z, a.w)));
        mx  = fmaxf(mx,  fmaxf(fmaxf(bq.x, bq.y), fmaxf(bq.z, bq.w)));
        mnv = fminf(mnv, fminf(fminf(a.x, a.y),  fminf(a.z, a.w)));
        mnv = fminf(mnv, fminf(fminf(bq.x, bq.y), fminf(bq.z, bq.w)));
    }
    const float sc  = g[c] * rsqrtf(vr[c] + EPS_);
    const float sel = (sc >= 0.f) ? mx : mnv;
    const float pv  = fmaf(sel - mn[c], sc, be[c]);
    ws[P_OFF + (b * K_ + k) * C_H_ + c] = pv;
}

// ---------------- Kernel 2: kv projection -> ck[b][k][c], cv[b][c][k]; BN-l coeffs ----------------
__global__ __launch_bounds__(256) void kv_kernel(
    const float* __restrict__ kv_w, const float* __restrict__ kv_b,
    const float* __restrict__ lg, const float* __restrict__ lb,
    const float* __restrict__ lm, const float* __restrict__ lv,
    float* __restrict__ ws)
{
    __shared__ __align__(16) float prow[C_H_];
    const int t   = threadIdx.x;
    const int bid = blockIdx.x;          // 512 blocks = 8 b * 64 k
    const int b   = bid >> 6;
    const int k   = bid & 63;

    if (t < C_H_ / 4) {
        reinterpret_cast<float4*>(prow)[t] =
            reinterpret_cast<const float4*>(ws + P_OFF + (b * K_ + k) * C_H_)[t];
    }
    __syncthreads();

    float a0 = kv_b[t];
    float a1 = kv_b[t + 256];
    const float* w0 = kv_w + (size_t)t * C_H_;
    const float* w1 = kv_w + (size_t)(t + 256) * C_H_;
#pragma unroll
    for (int c = 0; c < C_H_; c += 4) {
        const float4 pv  = *reinterpret_cast<const float4*>(prow + c);
        const float4 wv0 = *reinterpret_cast<const float4*>(w0 + c);
        const float4 wv1 = *reinterpret_cast<const float4*>(w1 + c);
        a0 = fmaf(wv0.x, pv.x, a0); a0 = fmaf(wv0.y, pv.y, a0);
        a0 = fmaf(wv0.z, pv.z, a0); a0 = fmaf(wv0.w, pv.w, a0);
        a1 = fmaf(wv1.x, pv.x, a1); a1 = fmaf(wv1.y, pv.y, a1);
        a1 = fmaf(wv1.z, pv.z, a1); a1 = fmaf(wv1.w, pv.w, a1);
    }
    ws[CK_OFF + (b * K_ + k) * C_L_ + t] = a0;
    ws[CV_OFF + (b * C_L_ + t) * K_ + k] = a1;

    if (bid == 0) {   // BN-l scale/shift precompute (once; kernel3 runs after)
        const float s = lg[t] * rsqrtf(lv[t] + EPS_);
        ws[SCL_OFF + t] = s;
        ws[SHF_OFF + t] = fmaf(-lm[t], s, lb[t]);
    }
}

// ---------------- Kernel 3: attention + softmax + PV + residual ----------------
// 256 blocks (1/CU; b = bid&7 -> XCD-pinned), 512 threads (8 waves/CU), 1 pixel/thread.
// ck + cv + coeffs all staged up-front (130.5 KB of 160 KB LDS) -> ONE barrier total;
// after it every wave runs phase A -> softmax -> phase B with zero synchronization.
__global__ __launch_bounds__(512, 2) void attn_kernel(
    const float* __restrict__ x_l,
    const float* __restrict__ reatt,
    const float* __restrict__ ws,
    float* __restrict__ out)
{
    __shared__ __align__(16) float ck_s[K_ * C_L_];   // 64 KB
    __shared__ __align__(16) float cv_s[C_L_ * K_];   // 64 KB
    __shared__ __align__(16) float scl_s[C_L_];
    __shared__ __align__(16) float shf_s[C_L_];
    __shared__ __align__(16) float rs_s[K_];

    const int t    = threadIdx.x;
    const int bid  = blockIdx.x;
    const int b    = bid & 7;
    const int tile = bid >> 3;                        // 0..31
    const int p0   = tile * 512 + t;                  // this thread's pixel

    // ---- stage everything (one barrier for the whole kernel) ----
    {
        const float4* srcK = reinterpret_cast<const float4*>(ws + CK_OFF + b * (K_ * C_L_));
        const float4* srcV = reinterpret_cast<const float4*>(ws + CV_OFF + b * (C_L_ * K_));
        float4* dK = reinterpret_cast<float4*>(ck_s);
        float4* dV = reinterpret_cast<float4*>(cv_s);
#pragma unroll
        for (int i = 0; i < 8; i++) {
            dK[t + 512 * i] = srcK[t + 512 * i];
            dV[t + 512 * i] = srcV[t + 512 * i];
        }
        if (t < C_L_) {
            scl_s[t] = ws[SCL_OFF + t];
            shf_s[t] = ws[SHF_OFF + t];
        }
        if (t < K_) rs_s[t] = reatt[t] * 0.125f;      // pre-scaled bias: (logit+r)*s = logit*s + r*s
    }

    const float* xb = x_l + (size_t)b * (C_L_ * NPIX_L) + p0;

    float acc[K_];
#pragma unroll
    for (int k = 0; k < K_; k++) acc[k] = 0.f;

    __syncthreads();

    // ---- phase A: logits (c ascending) ----
    float xa[4];
#pragma unroll
    for (int j = 0; j < 4; j++) xa[j] = xb[j * NPIX_L];

    for (int cc = 0; cc < C_L_; cc += 4) {
        // prefetch next c-group (clamped; tail prefetch never consumed)
        const int ncc = (cc + 4 < C_L_) ? (cc + 4) : cc;
        const float* nx = xb + ncc * NPIX_L;
        float nb[4];
#pragma unroll
        for (int j = 0; j < 4; j++) nb[j] = nx[j * NPIX_L];

        float xs[4];
#pragma unroll
        for (int j = 0; j < 4; j++) xs[j] = fmaf(xa[j], scl_s[cc + j], shf_s[cc + j]);

#pragma unroll
        for (int k = 0; k < K_; k++) {
            const float4 ckv = *reinterpret_cast<const float4*>(&ck_s[k * C_L_ + cc]);
            float a = acc[k];
            a = fmaf(ckv.x, xs[0], a);
            a = fmaf(ckv.y, xs[1], a);
            a = fmaf(ckv.z, xs[2], a);
            a = fmaf(ckv.w, xs[3], a);
            acc[k] = a;
        }
#pragma unroll
        for (int j = 0; j < 4; j++) xa[j] = nb[j];
    }

    // ---- softmax over k (registers) ----
    float m0 = -INFINITY;
#pragma unroll
    for (int k = 0; k < K_; k++) {
        acc[k] = fmaf(acc[k], 0.125f, rs_s[k]);
        m0 = fmaxf(m0, acc[k]);
    }
    float s0 = 0.f;
#pragma unroll
    for (int k = 0; k < K_; k++) {
        const float e = __expf(acc[k] - m0);
        acc[k] = e;
        s0 += e;
    }
    const float r0 = 1.f / s0;
#pragma unroll
    for (int k = 0; k < K_; k++) acc[k] *= r0;

    // ---- phase B: out = x_l + cv . w  (c descending for L2 reuse of phase-A tail) ----
    float* ob = out + (size_t)b * (C_L_ * NPIX_L) + p0;
    float xr = xb[(C_L_ - 1) * NPIX_L];
    for (int c = C_L_ - 1; c >= 0; c--) {
        const int pc = (c > 0) ? (c - 1) : 0;
        const float nr = xb[pc * NPIX_L];
        float pa = 0.f, pb = 0.f, pcv = 0.f, pd = 0.f;
#pragma unroll
        for (int kk = 0; kk < K_; kk += 4) {
            const float4 cvv = *reinterpret_cast<const float4*>(&cv_s[c * K_ + kk]);
            pa  = fmaf(cvv.x, acc[kk],     pa);
            pb  = fmaf(cvv.y, acc[kk + 1], pb);
            pcv = fmaf(cvv.z, acc[kk + 2], pcv);
            pd  = fmaf(cvv.w, acc[kk + 3], pd);
        }
        const float o = xr + ((pa + pb) + (pcv + pd));
        __builtin_nontemporal_store(o, ob + c * NPIX_L);
        xr = nr;
    }
}

extern "C" void kernel_launch(void* const* d_in, const int* in_sizes, int n_in,
                              void* d_out, int out_size, void* d_ws, size_t ws_size,
                              hipStream_t stream) {
    const float* x_h  = (const float*)d_in[0];
    const float* x_l  = (const float*)d_in[1];
    const float* hg   = (const float*)d_in[2];
    const float* hb   = (const float*)d_in[3];
    const float* hm   = (const float*)d_in[4];
    const float* hv   = (const float*)d_in[5];
    const float* kvw  = (const float*)d_in[6];
    const float* kvb  = (const float*)d_in[7];
    const float* lg   = (const float*)d_in[8];
    const float* lb   = (const float*)d_in[9];
    const float* lm   = (const float*)d_in[10];
    const float* lv   = (const float*)d_in[11];
    const float* ratt = (const float*)d_in[12];
    float* ws  = (float*)d_ws;
    float* out = (float*)d_out;

    pool_bn_kernel<<<256, 256, 0, stream>>>(x_h, hg, hb, hm, hv, ws);
    kv_kernel<<<512, 256, 0, stream>>>(kvw, kvb, lg, lb, lm, lv, ws);
    attn_kernel<<<256, 512, 0, stream>>>(x_l, ratt, ws, out);
}

// Round 3
// 329.151 us; speedup vs baseline: 1.4799x; 1.4799x over previous
//
#include <hip/hip_runtime.h>
#include <math.h>

#define B_     8
#define C_H_   128
#define C_L_   256
#define K_     64
#define NPIX_L 16384          // 128*128
#define EPS_   1e-5f

// ws layout: P (float) | B1 (bf16, swizzled) | B2 (bf16, swizzled) | bias (float)
#define P_OFF     0
#define P_SZ      (B_*K_*C_H_)                 // 65536 floats
#define B1_BYTE   (P_SZ*4)                     // 262144
#define B2_BYTE   (B1_BYTE + B_*K_*C_L_*2)     // +262144
#define BIAS_BYTE (B2_BYTE + B_*K_*C_L_*2)     // 512 floats

typedef short bf16x8 __attribute__((ext_vector_type(8)));   // 4 VGPRs = 8 bf16
typedef float f32x4  __attribute__((ext_vector_type(4)));

__device__ inline unsigned short f2bf(float f) {            // RNE fp32->bf16
    unsigned int u = __float_as_uint(f);
    u += 0x7FFFu + ((u >> 16) & 1u);
    return (unsigned short)(u >> 16);
}
__device__ inline unsigned int pack2bf(float lo, float hi) { // two bf16 in one u32
    unsigned int ul = __float_as_uint(lo);
    unsigned int uh = __float_as_uint(hi);
    ul = (ul + (0x7FFFu + ((ul >> 16) & 1u))) >> 16;
    uh = (uh + (0x7FFFu + ((uh >> 16) & 1u))) & 0xFFFF0000u;
    return ul | uh;
}

#define MFMA16(a, b, c) __builtin_amdgcn_mfma_f32_16x16x32_bf16((a), (b), (c), 0, 0, 0)

// ---------------- Kernel 1: BN + 8x8 max-pool of x_h -> p[b][k][c] ----------------
// BN monotone: max(BN(x)) = BN(max x) if scale>=0 else BN(min x).
__global__ __launch_bounds__(256) void pool_bn_kernel(
    const float* __restrict__ x_h,
    const float* __restrict__ g, const float* __restrict__ be,
    const float* __restrict__ mn, const float* __restrict__ vr,
    float* __restrict__ ws)
{
    const int t   = threadIdx.x;
    const int k   = t & 63;
    const int cl  = t >> 6;
    const int bid = blockIdx.x;    // 256 = 8 b * 32 cgroups
    const int b   = bid >> 5;
    const int c   = ((bid & 31) << 2) + cl;

    const float* plane = x_h + ((size_t)(b * C_H_ + c) << 12);
    const int ph = k >> 3, pw = k & 7;
    const float* p0 = plane + (ph * 8) * 64 + pw * 8;

    float mx = -INFINITY, mnv = INFINITY;
#pragma unroll
    for (int i = 0; i < 8; i++) {
        const float4 a  = *reinterpret_cast<const float4*>(p0 + i * 64);
        const float4 bq = *reinterpret_cast<const float4*>(p0 + i * 64 + 4);
        mx  = fmaxf(mx,  fmaxf(fmaxf(a.x, a.y),  fmaxf(a.z, a.w)));
        mx  = fmaxf(mx,  fmaxf(fmaxf(bq.x, bq.y), fmaxf(bq.z, bq.w)));
        mnv = fminf(mnv, fminf(fminf(a.x, a.y),  fminf(a.z, a.w)));
        mnv = fminf(mnv, fminf(fminf(bq.x, bq.y), fminf(bq.z, bq.w)));
    }
    const float sc  = g[c] * rsqrtf(vr[c] + EPS_);
    const float sel = (sc >= 0.f) ? mx : mnv;
    ws[P_OFF + (b * K_ + k) * C_H_ + c] = fmaf(sel - mn[c], sc, be[c]);
}

// ---------------- Kernel 2: kv projection -> swizzled bf16 B1/B2 + softmax bias ----------------
// B1[c][kk] = ck[kk][c]*scl[c]  (GEMM1 B-operand, frag-linear order)
// B2[kk][co] = cv[co][kk]       (GEMM2 B-operand, frag-linear order)
// bias[b][kk] = (sum_c shf[c]*ck[kk][c] + reatt[kk]) * 0.125   (BN shift + reatt folded)
__global__ __launch_bounds__(256) void kv_kernel(
    const float* __restrict__ kv_w, const float* __restrict__ kv_b,
    const float* __restrict__ lg, const float* __restrict__ lb,
    const float* __restrict__ lm, const float* __restrict__ lv,
    const float* __restrict__ ratt,
    float* __restrict__ ws)
{
    __shared__ __align__(16) float prow[C_H_];
    __shared__ float red[4];
    const int t   = threadIdx.x;
    const int bid = blockIdx.x;          // 512 = 8 b * 64 kk
    const int b   = bid >> 6;
    const int kk  = bid & 63;

    if (t < C_H_ / 4) {
        reinterpret_cast<float4*>(prow)[t] =
            reinterpret_cast<const float4*>(ws + P_OFF + (b * K_ + kk) * C_H_)[t];
    }
    __syncthreads();

    float a0 = kv_b[t];          // ck[b][kk][c=t]
    float a1 = kv_b[t + 256];    // cv[b][co=t][kk]
    const float* w0 = kv_w + (size_t)t * C_H_;
    const float* w1 = kv_w + (size_t)(t + 256) * C_H_;
#pragma unroll
    for (int c = 0; c < C_H_; c += 4) {
        const float4 pv  = *reinterpret_cast<const float4*>(prow + c);
        const float4 wv0 = *reinterpret_cast<const float4*>(w0 + c);
        const float4 wv1 = *reinterpret_cast<const float4*>(w1 + c);
        a0 = fmaf(wv0.x, pv.x, a0); a0 = fmaf(wv0.y, pv.y, a0);
        a0 = fmaf(wv0.z, pv.z, a0); a0 = fmaf(wv0.w, pv.w, a0);
        a1 = fmaf(wv1.x, pv.x, a1); a1 = fmaf(wv1.y, pv.y, a1);
        a1 = fmaf(wv1.z, pv.z, a1); a1 = fmaf(wv1.w, pv.w, a1);
    }

    // BN-l coeffs for channel t
    const float s = lg[t] * rsqrtf(lv[t] + EPS_);
    const float h = fmaf(-lm[t], s, lb[t]);

    // block-reduce sum_c h*a0  (bias from folded BN shift)
    float contrib = h * a0;
#pragma unroll
    for (int m = 1; m < 64; m <<= 1) contrib += __shfl_xor(contrib, m, 64);
    if ((t & 63) == 0) red[t >> 6] = contrib;
    __syncthreads();

    unsigned short* b1 = (unsigned short*)((char*)ws + B1_BYTE);
    unsigned short* b2 = (unsigned short*)((char*)ws + B2_BYTE);

    {   // B1 swizzle: value at (c=t, kk): s1=c>>5, lane=((c>>3)&3)*16 + (kk&15), j=c&7, n=kk>>4
        const int s1 = t >> 5, j = t & 7;
        const int l  = ((t >> 3) & 3) * 16 + (kk & 15);
        const int n  = kk >> 4;
        b1[((((b * 8 + s1) * 4 + n) * 64) + l) * 8 + j] = f2bf(a0 * s);
    }
    {   // B2 swizzle: value at (kk, co=t): s2=kk>>5, lane=((kk>>3)&3)*16 + (t&15), j=kk&7, n=t>>4
        const int s2 = kk >> 5, j2 = kk & 7;
        const int l2 = ((kk >> 3) & 3) * 16 + (t & 15);
        const int n2 = t >> 4;
        b2[((((b * 2 + s2) * 16 + n2) * 64) + l2) * 8 + j2] = f2bf(a1);
    }
    if (t == 0) {
        float* bia = (float*)((char*)ws + BIAS_BYTE);
        bia[b * K_ + kk] = (red[0] + red[1] + red[2] + red[3] + ratt[kk]) * 0.125f;
    }
}

// ---------------- Kernel 3: MFMA attention ----------------
// 1024 blocks (b=bid&7 XCD-pinned), 256 threads = 4 waves, 32 px/wave (2 M-tiles).
// GEMM1: S[32px x 64k] = X(bf16) @ B1, K=256 (8 steps). Softmax in C-layout regs.
// W -> LDS (padded stride 72) -> A-layout frags. GEMM2: Out[32px x 256c] = W @ B2, K=64.
// No __syncthreads: each wave owns its LDS rows.
__global__ __launch_bounds__(256, 4) void attn_mfma(
    const float* __restrict__ x_l,
    const float* __restrict__ ws_f,
    float* __restrict__ out)
{
    __shared__ unsigned short wa[128 * 72];   // 18 KB, +8 pad per row -> <=2-way banks

    const int t    = threadIdx.x;
    const int lane = t & 63;
    const int wid  = t >> 6;
    const int bid  = blockIdx.x;
    const int b    = bid & 7;
    const int tile = bid >> 3;                 // 0..127
    const int pw0  = tile * 128 + wid * 32;    // wave's global pixel base
    const int r16  = lane & 15;
    const int q    = lane >> 4;

    const unsigned short* b1 = (const unsigned short*)((const char*)ws_f + B1_BYTE);
    const unsigned short* b2 = (const unsigned short*)((const char*)ws_f + B2_BYTE);
    const float* biasf = (const float*)((const char*)ws_f + BIAS_BYTE) + b * K_;
    const float* xb = x_l + (size_t)b * (C_L_ * NPIX_L);

    float bl[4];
#pragma unroll
    for (int n = 0; n < 4; n++) bl[n] = biasf[16 * n + r16];   // bias for kk=16n+r16

    // ---- GEMM1 ----
    f32x4 acc1[2][4] = {};
    union ABu { bf16x8 v; unsigned int u[4]; };
    const float* xpx = xb + pw0 + r16;

#pragma unroll
    for (int s = 0; s < 8; s++) {
        const int c0 = 32 * s + q * 8;
        float xv0[8], xv1[8];
#pragma unroll
        for (int j = 0; j < 8; j++) {
            xv0[j] = xpx[(size_t)(c0 + j) * NPIX_L];        // m=0 tile
            xv1[j] = xpx[(size_t)(c0 + j) * NPIX_L + 16];   // m=1 tile
        }
        ABu a0f, a1f;
#pragma unroll
        for (int jj = 0; jj < 4; jj++) {
            a0f.u[jj] = pack2bf(xv0[2 * jj], xv0[2 * jj + 1]);
            a1f.u[jj] = pack2bf(xv1[2 * jj], xv1[2 * jj + 1]);
        }
        const bf16x8* bp = ((const bf16x8*)b1) + ((b * 8 + s) * 4) * 64 + lane;
#pragma unroll
        for (int n = 0; n < 4; n++) {
            const bf16x8 bfr = bp[n * 64];
            acc1[0][n] = MFMA16(a0f.v, bfr, acc1[0][n]);
            acc1[1][n] = MFMA16(a1f.v, bfr, acc1[1][n]);
        }
    }

    // ---- softmax (C-layout: px = 16m + 4q + r, kk = 16n + r16) + W -> LDS ----
    const int plbase = wid * 32;
#pragma unroll
    for (int m = 0; m < 2; m++) {
#pragma unroll
        for (int r = 0; r < 4; r++) {
            float e0 = fmaf(acc1[m][0][r], 0.125f, bl[0]);
            float e1 = fmaf(acc1[m][1][r], 0.125f, bl[1]);
            float e2 = fmaf(acc1[m][2][r], 0.125f, bl[2]);
            float e3 = fmaf(acc1[m][3][r], 0.125f, bl[3]);
            float mx = fmaxf(fmaxf(e0, e1), fmaxf(e2, e3));
#pragma unroll
            for (int msk = 1; msk < 16; msk <<= 1) mx = fmaxf(mx, __shfl_xor(mx, msk, 64));
            e0 = __expf(e0 - mx); e1 = __expf(e1 - mx);
            e2 = __expf(e2 - mx); e3 = __expf(e3 - mx);
            float sm = (e0 + e1) + (e2 + e3);
#pragma unroll
            for (int msk = 1; msk < 16; msk <<= 1) sm += __shfl_xor(sm, msk, 64);
            const float inv = 1.f / sm;
            unsigned short* wp = wa + (plbase + 16 * m + q * 4 + r) * 72 + r16;
            wp[0]  = f2bf(e0 * inv);
            wp[16] = f2bf(e1 * inv);
            wp[32] = f2bf(e2 * inv);
            wp[48] = f2bf(e3 * inv);
        }
    }

    // ---- W A-frags from LDS (A[px=r16][kk = 32s + 8q + j]) ----
    bf16x8 af[2][2];
#pragma unroll
    for (int m = 0; m < 2; m++)
#pragma unroll
        for (int s = 0; s < 2; s++)
            af[m][s] = *(const bf16x8*)(wa + (plbase + 16 * m + r16) * 72 + 32 * s + q * 8);

    // ---- GEMM2 + residual epilogue ----
    float* ob = out + (size_t)b * (C_L_ * NPIX_L);
#pragma unroll
    for (int nc = 0; nc < 4; nc++) {
        f32x4 acc2[2][4] = {};
#pragma unroll
        for (int s = 0; s < 2; s++) {
            const bf16x8* bp2 = ((const bf16x8*)b2) + ((b * 2 + s) * 16 + nc * 4) * 64 + lane;
#pragma unroll
            for (int nn = 0; nn < 4; nn++) {
                const bf16x8 bfr = bp2[nn * 64];
                acc2[0][nn] = MFMA16(af[0][s], bfr, acc2[0][nn]);
                acc2[1][nn] = MFMA16(af[1][s], bfr, acc2[1][nn]);
            }
        }
#pragma unroll
        for (int m = 0; m < 2; m++) {
#pragma unroll
            for (int nn = 0; nn < 4; nn++) {
                const int co = 16 * (nc * 4 + nn) + r16;
                const size_t base = (size_t)co * NPIX_L + pw0 + 16 * m + q * 4;
#pragma unroll
                for (int r = 0; r < 4; r++) {
                    ob[base + r] = acc2[m][nn][r] + xb[base + r];
                }
            }
        }
    }
}

extern "C" void kernel_launch(void* const* d_in, const int* in_sizes, int n_in,
                              void* d_out, int out_size, void* d_ws, size_t ws_size,
                              hipStream_t stream) {
    const float* x_h  = (const float*)d_in[0];
    const float* x_l  = (const float*)d_in[1];
    const float* hg   = (const float*)d_in[2];
    const float* hb   = (const float*)d_in[3];
    const float* hm   = (const float*)d_in[4];
    const float* hv   = (const float*)d_in[5];
    const float* kvw  = (const float*)d_in[6];
    const float* kvb  = (const float*)d_in[7];
    const float* lg   = (const float*)d_in[8];
    const float* lb   = (const float*)d_in[9];
    const float* lm   = (const float*)d_in[10];
    const float* lv   = (const float*)d_in[11];
    const float* ratt = (const float*)d_in[12];
    float* ws  = (float*)d_ws;
    float* out = (float*)d_out;

    pool_bn_kernel<<<256, 256, 0, stream>>>(x_h, hg, hb, hm, hv, ws);
    kv_kernel<<<512, 256, 0, stream>>>(kvw, kvb, lg, lb, lm, lv, ratt, ws);
    attn_mfma<<<1024, 256, 0, stream>>>(x_l, ws, out);
}